// Round 1
// baseline (503.578 us; speedup 1.0000x reference)
//
#include <hip/hip_runtime.h>
#include <hip/hip_bf16.h>

#define D 128
#define NPB 16  // nodes per block in logit kernel

// ---------------------------------------------------------------------------
// Kernel 1: logit[i] = sum_j w2[j] * tanh( dot(N[i,:], W1[j,:]) )
// Block = 256 threads (4 waves). Threads 0-127 -> node (g*2+0), 128-255 -> node
// (g*2+1), j = tid & 127. W1^T staged in LDS in K-chunks of 32 rows with +1
// padding (stride 129) -> conflict-free ds_read_b32 with immediate offsets.
// Per-wave partial reduced via shfl, combined across the 2 waves of a node
// via atomicAdd into logit (logit is zeroed beforehand).
// ---------------------------------------------------------------------------
__global__ __launch_bounds__(256) void logit_kernel(
    const float* __restrict__ Nm, const float* __restrict__ W1,
    const float* __restrict__ w2, float* __restrict__ logit, int n_nodes) {
  __shared__ float w1t[32 * 129];  // w1t[kl*129 + j] = W1[j][c*32+kl]
  const int tid  = threadIdx.x;
  const int j    = tid & 127;
  const int half = tid >> 7;  // 0 or 1
  const int base = blockIdx.x * NPB;

  float acc[8];
#pragma unroll
  for (int g = 0; g < 8; ++g) acc[g] = 0.f;

  for (int c = 0; c < 4; ++c) {
    __syncthreads();  // protect previous chunk's readers
    // stage chunk: coalesced global read, conflict-free LDS write
    for (int idx = tid; idx < 128 * 32; idx += 256) {
      int kl = idx & 31, jj = idx >> 5;
      w1t[kl * 129 + jj] = W1[jj * 128 + c * 32 + kl];
    }
    __syncthreads();
#pragma unroll
    for (int g = 0; g < 8; ++g) {
      int node = base + g * 2 + half;
      if (node < n_nodes) {
        const float4* nrow =
            reinterpret_cast<const float4*>(Nm + (size_t)node * D + c * 32);
        float a = acc[g];
#pragma unroll
        for (int k4 = 0; k4 < 8; ++k4) {
          float4 nv = nrow[k4];  // wave-uniform address -> L1 broadcast
          int kl = k4 * 4;
          a += nv.x * w1t[(kl + 0) * 129 + j];
          a += nv.y * w1t[(kl + 1) * 129 + j];
          a += nv.z * w1t[(kl + 2) * 129 + j];
          a += nv.w * w1t[(kl + 3) * 129 + j];
        }
        acc[g] = a;
      }
    }
  }

  const float w2j = w2[j];
#pragma unroll
  for (int g = 0; g < 8; ++g) {
    int node = base + g * 2 + half;
    float t = tanhf(acc[g]) * w2j;
#pragma unroll
    for (int off = 32; off; off >>= 1) t += __shfl_down(t, off);
    if ((tid & 63) == 0 && node < n_nodes) atomicAdd(&logit[node], t);
  }
}

// ---------------------------------------------------------------------------
// Kernel 2: denom[d] += exp(logit[src[e]]) for each edge.
// No segment-max needed: |logit| <= ||w2||_1 ~ 9, exp stays in f32 range;
// a = exp(e)/sum(exp(e)) is mathematically identical to max-subtracted form.
// ---------------------------------------------------------------------------
__global__ __launch_bounds__(256) void denom_kernel(
    const int* __restrict__ src, const int* __restrict__ dst,
    const float* __restrict__ logit, float* __restrict__ denom, int n_edges) {
  int e = blockIdx.x * 256 + threadIdx.x;
  if (e < n_edges) {
    float ex = expf(logit[src[e]]);
    atomicAdd(&denom[dst[e]], ex);
  }
}

// ---------------------------------------------------------------------------
// Kernel 3: out[dst[e], :] += a_e * N[src[e], :], one wave per edge.
// Lanes cover the 128 features as two coalesced 256B chunks.
// ---------------------------------------------------------------------------
__global__ __launch_bounds__(256) void scatter_kernel(
    const int* __restrict__ src, const int* __restrict__ dst,
    const float* __restrict__ logit, const float* __restrict__ denom,
    const float* __restrict__ Nm, float* __restrict__ out, int n_edges) {
  int wave = (blockIdx.x * 256 + threadIdx.x) >> 6;
  int lane = threadIdx.x & 63;
  if (wave >= n_edges) return;
  int s = src[wave];
  int d = dst[wave];
  float a = expf(logit[s]) / denom[d];
  float v0 = Nm[(size_t)s * D + lane];
  float v1 = Nm[(size_t)s * D + 64 + lane];
  atomicAdd(&out[(size_t)d * D + lane], a * v0);
  atomicAdd(&out[(size_t)d * D + 64 + lane], a * v1);
}

extern "C" void kernel_launch(void* const* d_in, const int* in_sizes, int n_in,
                              void* d_out, int out_size, void* d_ws,
                              size_t ws_size, hipStream_t stream) {
  const float* Nm  = (const float*)d_in[0];
  const float* W1  = (const float*)d_in[1];
  const float* w2  = (const float*)d_in[2];
  const int*   src = (const int*)d_in[3];
  const int*   dst = (const int*)d_in[4];
  float* out = (float*)d_out;

  const int n_nodes = in_sizes[0] / D;
  const int n_edges = in_sizes[3];

  // workspace layout: [logit: n_pad floats][denom: n_pad floats]
  const int n_pad = (n_nodes + 63) & ~63;
  float* logit = (float*)d_ws;
  float* denom = logit + n_pad;

  // zero accumulators (graph-capturable async memsets)
  hipMemsetAsync(logit, 0, (size_t)2 * n_pad * sizeof(float), stream);
  hipMemsetAsync(out, 0, (size_t)out_size * sizeof(float), stream);

  // 1) per-node logits
  int nblk1 = (n_nodes + NPB - 1) / NPB;
  logit_kernel<<<nblk1, 256, 0, stream>>>(Nm, W1, w2, logit, n_nodes);

  // 2) softmax denominators
  int nblk2 = (n_edges + 255) / 256;
  denom_kernel<<<nblk2, 256, 0, stream>>>(src, dst, logit, denom, n_edges);

  // 3) weighted scatter-sum (wave per edge)
  int nblk3 = (n_edges + 3) / 4;  // 4 waves per 256-thread block
  scatter_kernel<<<nblk3, 256, 0, stream>>>(src, dst, logit, denom, Nm, out,
                                            n_edges);
}

// Round 2
// 286.019 us; speedup vs baseline: 1.7606x; 1.7606x over previous
//
#include <hip/hip_runtime.h>
#include <hip/hip_bf16.h>

#define D 128
#define NPB 16        // nodes per block in logit kernel
#define SCAN_ELEMS 1024  // elements per scan block (256 thr x 4)

// ---------------------------------------------------------------------------
// Kernel 1: logit[i] = sum_j w2[j] * tanh( dot(N[i,:], W1[j,:]) )
// (unchanged from R1 — passed, ~VALU-bound; optimize next round)
// ---------------------------------------------------------------------------
__global__ __launch_bounds__(256) void logit_kernel(
    const float* __restrict__ Nm, const float* __restrict__ W1,
    const float* __restrict__ w2, float* __restrict__ logit, int n_nodes) {
  __shared__ float w1t[32 * 129];
  const int tid  = threadIdx.x;
  const int j    = tid & 127;
  const int half = tid >> 7;
  const int base = blockIdx.x * NPB;

  float acc[8];
#pragma unroll
  for (int g = 0; g < 8; ++g) acc[g] = 0.f;

  for (int c = 0; c < 4; ++c) {
    __syncthreads();
    for (int idx = tid; idx < 128 * 32; idx += 256) {
      int kl = idx & 31, jj = idx >> 5;
      w1t[kl * 129 + jj] = W1[jj * 128 + c * 32 + kl];
    }
    __syncthreads();
#pragma unroll
    for (int g = 0; g < 8; ++g) {
      int node = base + g * 2 + half;
      if (node < n_nodes) {
        const float4* nrow =
            reinterpret_cast<const float4*>(Nm + (size_t)node * D + c * 32);
        float a = acc[g];
#pragma unroll
        for (int k4 = 0; k4 < 8; ++k4) {
          float4 nv = nrow[k4];
          int kl = k4 * 4;
          a += nv.x * w1t[(kl + 0) * 129 + j];
          a += nv.y * w1t[(kl + 1) * 129 + j];
          a += nv.z * w1t[(kl + 2) * 129 + j];
          a += nv.w * w1t[(kl + 3) * 129 + j];
        }
        acc[g] = a;
      }
    }
  }

  const float w2j = w2[j];
#pragma unroll
  for (int g = 0; g < 8; ++g) {
    int node = base + g * 2 + half;
    float t = tanhf(acc[g]) * w2j;
#pragma unroll
    for (int off = 32; off; off >>= 1) t += __shfl_down(t, off);
    if ((tid & 63) == 0 && node < n_nodes) atomicAdd(&logit[node], t);
  }
}

// ---------------------------------------------------------------------------
// CSR build: histogram -> hierarchical exclusive scan -> fill sorted arrays
// ---------------------------------------------------------------------------
__global__ __launch_bounds__(256) void hist_kernel(const int* __restrict__ dst,
                                                   int* __restrict__ count,
                                                   int n_edges) {
  int e = blockIdx.x * 256 + threadIdx.x;
  if (e < n_edges) atomicAdd(&count[dst[e]], 1);
}

__global__ __launch_bounds__(256) void scanA_kernel(
    const int* __restrict__ count, int* __restrict__ offsets,
    int* __restrict__ bsums, int n) {
  __shared__ int sdata[256];
  int tid = threadIdx.x;
  int base = blockIdx.x * SCAN_ELEMS + tid * 4;
  int c0 = (base + 0 < n) ? count[base + 0] : 0;
  int c1 = (base + 1 < n) ? count[base + 1] : 0;
  int c2 = (base + 2 < n) ? count[base + 2] : 0;
  int c3 = (base + 3 < n) ? count[base + 3] : 0;
  int s = c0 + c1 + c2 + c3;
  sdata[tid] = s;
  __syncthreads();
  for (int d = 1; d < 256; d <<= 1) {  // Hillis-Steele inclusive scan
    int v = (tid >= d) ? sdata[tid - d] : 0;
    __syncthreads();
    sdata[tid] += v;
    __syncthreads();
  }
  int tb = sdata[tid] - s;  // exclusive base for this thread
  if (base + 0 < n) offsets[base + 0] = tb;
  if (base + 1 < n) offsets[base + 1] = tb + c0;
  if (base + 2 < n) offsets[base + 2] = tb + c0 + c1;
  if (base + 3 < n) offsets[base + 3] = tb + c0 + c1 + c2;
  if (tid == 255) bsums[blockIdx.x] = sdata[255];
}

__global__ void scanB_kernel(int* __restrict__ bsums, int nb) {
  if (threadIdx.x == 0 && blockIdx.x == 0) {
    int run = 0;
    for (int i = 0; i < nb; ++i) {
      int t = bsums[i];
      bsums[i] = run;
      run += t;
    }
  }
}

__global__ __launch_bounds__(256) void scanC_kernel(
    int* __restrict__ offsets, const int* __restrict__ bsums,
    int* __restrict__ cursor, int n, int n_edges) {
  int base = blockIdx.x * SCAN_ELEMS + threadIdx.x * 4;
  int add = bsums[blockIdx.x];
#pragma unroll
  for (int k = 0; k < 4; ++k) {
    int idx = base + k;
    if (idx < n) {
      int v = offsets[idx] + add;
      offsets[idx] = v;
      cursor[idx] = v;
    }
  }
  if (blockIdx.x == 0 && threadIdx.x == 0) offsets[n] = n_edges;
}

__global__ __launch_bounds__(256) void fill_kernel(
    const int* __restrict__ src, const int* __restrict__ dst,
    const float* __restrict__ logit, int* __restrict__ cursor,
    int* __restrict__ ssrc, float* __restrict__ sex, int n_edges) {
  int e = blockIdx.x * 256 + threadIdx.x;
  if (e < n_edges) {
    int d = dst[e];
    int s = src[e];
    int pos = atomicAdd(&cursor[d], 1);
    ssrc[pos] = s;
    sex[pos] = expf(logit[s]);
  }
}

// ---------------------------------------------------------------------------
// Accumulate: one wave per dst node. Register accumulation, single coalesced
// output write per row. No output atomics, no output memset needed.
// ---------------------------------------------------------------------------
__global__ __launch_bounds__(256) void accum_kernel(
    const int* __restrict__ offsets, const int* __restrict__ ssrc,
    const float* __restrict__ sex, const float* __restrict__ Nm,
    float* __restrict__ out, int n_nodes) {
  int node = (blockIdx.x * 256 + threadIdx.x) >> 6;
  int lane = threadIdx.x & 63;
  if (node >= n_nodes) return;
  int beg = offsets[node];
  int end = offsets[node + 1];
  float acc0 = 0.f, acc1 = 0.f, den = 0.f;
  int e = beg;
  for (; e + 1 < end; e += 2) {  // 2x unroll for load ILP
    int s0 = ssrc[e], s1 = ssrc[e + 1];
    float x0 = sex[e], x1 = sex[e + 1];
    float a00 = Nm[(size_t)s0 * D + lane];
    float a01 = Nm[(size_t)s0 * D + 64 + lane];
    float a10 = Nm[(size_t)s1 * D + lane];
    float a11 = Nm[(size_t)s1 * D + 64 + lane];
    den += x0 + x1;
    acc0 += x0 * a00 + x1 * a10;
    acc1 += x0 * a01 + x1 * a11;
  }
  if (e < end) {
    int s0 = ssrc[e];
    float x0 = sex[e];
    den += x0;
    acc0 += x0 * Nm[(size_t)s0 * D + lane];
    acc1 += x0 * Nm[(size_t)s0 * D + 64 + lane];
  }
  float inv = (end > beg) ? 1.0f / den : 0.f;
  out[(size_t)node * D + lane] = acc0 * inv;
  out[(size_t)node * D + 64 + lane] = acc1 * inv;
}

// ---------------------------------------------------------------------------
// Fallback path (R1): per-edge atomics — used only if ws_size is too small.
// ---------------------------------------------------------------------------
__global__ __launch_bounds__(256) void denom_kernel(
    const int* __restrict__ src, const int* __restrict__ dst,
    const float* __restrict__ logit, float* __restrict__ denom, int n_edges) {
  int e = blockIdx.x * 256 + threadIdx.x;
  if (e < n_edges) {
    float ex = expf(logit[src[e]]);
    atomicAdd(&denom[dst[e]], ex);
  }
}

__global__ __launch_bounds__(256) void scatter_kernel(
    const int* __restrict__ src, const int* __restrict__ dst,
    const float* __restrict__ logit, const float* __restrict__ denom,
    const float* __restrict__ Nm, float* __restrict__ out, int n_edges) {
  int wave = (blockIdx.x * 256 + threadIdx.x) >> 6;
  int lane = threadIdx.x & 63;
  if (wave >= n_edges) return;
  int s = src[wave];
  int d = dst[wave];
  float a = expf(logit[s]) / denom[d];
  float v0 = Nm[(size_t)s * D + lane];
  float v1 = Nm[(size_t)s * D + 64 + lane];
  atomicAdd(&out[(size_t)d * D + lane], a * v0);
  atomicAdd(&out[(size_t)d * D + 64 + lane], a * v1);
}

static inline char* align_up(char* p, size_t a) {
  return (char*)(((uintptr_t)p + a - 1) & ~(uintptr_t)(a - 1));
}

extern "C" void kernel_launch(void* const* d_in, const int* in_sizes, int n_in,
                              void* d_out, int out_size, void* d_ws,
                              size_t ws_size, hipStream_t stream) {
  const float* Nm  = (const float*)d_in[0];
  const float* W1  = (const float*)d_in[1];
  const float* w2  = (const float*)d_in[2];
  const int*   src = (const int*)d_in[3];
  const int*   dst = (const int*)d_in[4];
  float* out = (float*)d_out;

  const int n_nodes = in_sizes[0] / D;
  const int n_edges = in_sizes[3];
  const int n_pad = (n_nodes + 63) & ~63;
  const int nb_scan = (n_nodes + SCAN_ELEMS - 1) / SCAN_ELEMS;

  // carve workspace
  char* p = (char*)d_ws;
  float* logit = (float*)p;            p = align_up(p + (size_t)n_pad * 4, 256);
  int* count   = (int*)p;              p = align_up(p + (size_t)n_nodes * 4, 256);
  int* offsets = (int*)p;              p = align_up(p + (size_t)(n_nodes + 1) * 4, 256);
  int* cursor  = (int*)p;              p = align_up(p + (size_t)n_nodes * 4, 256);
  int* bsums   = (int*)p;              p = align_up(p + (size_t)nb_scan * 4, 256);
  int* ssrc    = (int*)p;              p = align_up(p + (size_t)n_edges * 4, 256);
  float* sex   = (float*)p;            p = align_up(p + (size_t)n_edges * 4, 256);
  size_t needed = (size_t)(p - (char*)d_ws);

  // 1) per-node logits (both paths)
  hipMemsetAsync(logit, 0, (size_t)n_pad * sizeof(float), stream);
  int nblk1 = (n_nodes + NPB - 1) / NPB;
  logit_kernel<<<nblk1, 256, 0, stream>>>(Nm, W1, w2, logit, n_nodes);

  int eblk = (n_edges + 255) / 256;

  if (ws_size >= needed) {
    // ---- CSR path ----
    hipMemsetAsync(count, 0, (size_t)n_nodes * sizeof(int), stream);
    hist_kernel<<<eblk, 256, 0, stream>>>(dst, count, n_edges);
    scanA_kernel<<<nb_scan, 256, 0, stream>>>(count, offsets, bsums, n_nodes);
    scanB_kernel<<<1, 64, 0, stream>>>(bsums, nb_scan);
    scanC_kernel<<<nb_scan, 256, 0, stream>>>(offsets, bsums, cursor, n_nodes,
                                              n_edges);
    fill_kernel<<<eblk, 256, 0, stream>>>(src, dst, logit, cursor, ssrc, sex,
                                          n_edges);
    int ablk = (n_nodes + 3) / 4;  // 4 waves (nodes) per block
    accum_kernel<<<ablk, 256, 0, stream>>>(offsets, ssrc, sex, Nm, out,
                                           n_nodes);
  } else {
    // ---- fallback: R1 atomic path ----
    float* denom = logit + n_pad;  // fits: R1 used this layout
    hipMemsetAsync(denom, 0, (size_t)n_pad * sizeof(float), stream);
    hipMemsetAsync(out, 0, (size_t)out_size * sizeof(float), stream);
    denom_kernel<<<eblk, 256, 0, stream>>>(src, dst, logit, denom, n_edges);
    int nblk3 = (n_edges + 3) / 4;
    scatter_kernel<<<nblk3, 256, 0, stream>>>(src, dst, logit, denom, Nm, out,
                                              n_edges);
  }
}

// Round 3
// 190.013 us; speedup vs baseline: 2.6502x; 1.5053x over previous
//
#include <hip/hip_runtime.h>
#include <hip/hip_bf16.h>

#define D 128
#define NPB 16           // nodes per block in fallback logit kernel
#define SCAN_ELEMS 1024  // elements per scan block (256 thr x 4)

typedef __attribute__((ext_vector_type(8))) short bf16x8;
typedef __attribute__((ext_vector_type(4))) float f32x4;

__device__ __forceinline__ unsigned short f2bf_rne(float f) {
  unsigned u = __float_as_uint(f);
  unsigned r = (u + 0x7FFFu + ((u >> 16) & 1u)) >> 16;
  return (unsigned short)r;
}

__device__ __forceinline__ float fast_tanh(float x) {
  // tanh(x) = 1 - 2/(exp(2x)+1); exp overflow -> inf -> 1, underflow -> -1.
  float e = __expf(2.0f * x);
  return 1.0f - 2.0f / (e + 1.0f);
}

// ---------------------------------------------------------------------------
// W1 -> bf16 hi/lo split (one-time, 16384 elements)
// ---------------------------------------------------------------------------
__global__ __launch_bounds__(256) void w1_convert_kernel(
    const float* __restrict__ W1, unsigned short* __restrict__ w1hi,
    unsigned short* __restrict__ w1lo) {
  int i = blockIdx.x * 256 + threadIdx.x;
  float x = W1[i];
  unsigned short h = f2bf_rne(x);
  float hf = __uint_as_float((unsigned)h << 16);
  w1hi[i] = h;
  w1lo[i] = f2bf_rne(x - hf);
}

// ---------------------------------------------------------------------------
// logit[i] = sum_j w2[j] * tanh( dot(N[i,:], W1[j,:]) )  via split-bf16 MFMA.
// Block = 256 thr (4 waves), 64 nodes. Wave w owns j-tiles {2w, 2w+1}; its 16
// B-frags (hi+lo) preload to registers. A (node rows) staged f32->bf16 hi/lo
// in XOR-swizzled LDS ((row&7)<<4 on byte offset; applied on write AND read).
// MFMA C layout (HW-verified): col=lane&15 (j), row=(lane>>4)*4+reg (node).
// Epilogue: tanh * w2, shfl_xor reduce over 16 lanes, 4 partial atomics/node.
// ---------------------------------------------------------------------------
__global__ __launch_bounds__(256, 2) void logit_mfma_kernel(
    const float* __restrict__ Nm, const unsigned short* __restrict__ w1hi,
    const unsigned short* __restrict__ w1lo, const float* __restrict__ w2,
    float* __restrict__ logit, int n_nodes) {
  __shared__ unsigned short lhi[64 * 128];
  __shared__ unsigned short llo[64 * 128];
  const int tid = threadIdx.x;
  const int w = tid >> 6;
  const int l = tid & 63;
  const int lg = l >> 4;  // lane group 0..3 (k-chunk selector)
  const int ln = l & 15;  // row/col within fragment
  const int base = blockIdx.x * 64;

  // ---- preload B fragments (W1^T) for this wave's two j-tiles ----
  bf16x8 Bh[2][4], Bl[2][4];
#pragma unroll
  for (int ntl = 0; ntl < 2; ++ntl) {
    int n = (w * 2 + ntl) * 16 + ln;  // W1 row = output feature j
#pragma unroll
    for (int kt = 0; kt < 4; ++kt) {
      int k = kt * 32 + lg * 8;
      Bh[ntl][kt] = *(const bf16x8*)(w1hi + n * 128 + k);
      Bl[ntl][kt] = *(const bf16x8*)(w1lo + n * 128 + k);
    }
  }

  // ---- stage A: 64 rows of N, f32 -> bf16 hi/lo, swizzled LDS ----
#pragma unroll
  for (int i = 0; i < 8; ++i) {
    int flat = tid + i * 256;  // float4 index, 2048 total
    int row = flat >> 5;       // 32 float4 per 128-f32 row
    int c4 = flat & 31;
    int grow = base + row;
    if (grow >= n_nodes) grow = n_nodes - 1;  // clamp (writes guarded later)
    float4 v = *(const float4*)(Nm + (size_t)grow * D + c4 * 4);
    unsigned short h0 = f2bf_rne(v.x), h1 = f2bf_rne(v.y);
    unsigned short h2 = f2bf_rne(v.z), h3 = f2bf_rne(v.w);
    unsigned short o0 = f2bf_rne(v.x - __uint_as_float((unsigned)h0 << 16));
    unsigned short o1 = f2bf_rne(v.y - __uint_as_float((unsigned)h1 << 16));
    unsigned short o2 = f2bf_rne(v.z - __uint_as_float((unsigned)h2 << 16));
    unsigned short o3 = f2bf_rne(v.w - __uint_as_float((unsigned)h3 << 16));
    int boff = (c4 * 8) ^ ((row & 7) << 4);  // byte offset within row
    *(ushort4*)((char*)lhi + row * 256 + boff) = make_ushort4(h0, h1, h2, h3);
    *(ushort4*)((char*)llo + row * 256 + boff) = make_ushort4(o0, o1, o2, o3);
  }
  __syncthreads();

  // ---- MFMA main: 4 node-tiles x 2 j-tiles x 4 k-tiles x 3 (split) ----
  f32x4 acc[4][2];
#pragma unroll
  for (int mt = 0; mt < 4; ++mt)
#pragma unroll
    for (int ntl = 0; ntl < 2; ++ntl) acc[mt][ntl] = (f32x4){0.f, 0.f, 0.f, 0.f};

#pragma unroll
  for (int mt = 0; mt < 4; ++mt) {
    int row = mt * 16 + ln;  // A fragment row = node within block
    bf16x8 Ah[4], Al[4];
#pragma unroll
    for (int kt = 0; kt < 4; ++kt) {
      int boff = (kt * 64 + lg * 16) ^ ((row & 7) << 4);
      Ah[kt] = *(const bf16x8*)((const char*)lhi + row * 256 + boff);
      Al[kt] = *(const bf16x8*)((const char*)llo + row * 256 + boff);
    }
#pragma unroll
    for (int ntl = 0; ntl < 2; ++ntl) {
#pragma unroll
      for (int kt = 0; kt < 4; ++kt) {
        acc[mt][ntl] = __builtin_amdgcn_mfma_f32_16x16x32_bf16(
            Ah[kt], Bh[ntl][kt], acc[mt][ntl], 0, 0, 0);
        acc[mt][ntl] = __builtin_amdgcn_mfma_f32_16x16x32_bf16(
            Ah[kt], Bl[ntl][kt], acc[mt][ntl], 0, 0, 0);
        acc[mt][ntl] = __builtin_amdgcn_mfma_f32_16x16x32_bf16(
            Al[kt], Bh[ntl][kt], acc[mt][ntl], 0, 0, 0);
      }
    }
  }

  // ---- epilogue: tanh * w2, reduce over j (16 lanes), partial atomics ----
  float w2a = w2[(w * 2 + 0) * 16 + ln];
  float w2b = w2[(w * 2 + 1) * 16 + ln];
#pragma unroll
  for (int mt = 0; mt < 4; ++mt) {
    float s0 = fast_tanh(acc[mt][0][0]) * w2a + fast_tanh(acc[mt][1][0]) * w2b;
    float s1 = fast_tanh(acc[mt][0][1]) * w2a + fast_tanh(acc[mt][1][1]) * w2b;
    float s2 = fast_tanh(acc[mt][0][2]) * w2a + fast_tanh(acc[mt][1][2]) * w2b;
    float s3 = fast_tanh(acc[mt][0][3]) * w2a + fast_tanh(acc[mt][1][3]) * w2b;
#pragma unroll
    for (int mask = 1; mask < 16; mask <<= 1) {
      s0 += __shfl_xor(s0, mask);
      s1 += __shfl_xor(s1, mask);
      s2 += __shfl_xor(s2, mask);
      s3 += __shfl_xor(s3, mask);
    }
    if (ln < 4) {
      float sv = (ln == 0) ? s0 : (ln == 1) ? s1 : (ln == 2) ? s2 : s3;
      int node = base + mt * 16 + lg * 4 + ln;
      if (node < n_nodes) atomicAdd(&logit[node], sv);
    }
  }
}

// ---------------------------------------------------------------------------
// Fallback scalar logit kernel (only if ws too small for bf16 W1 split)
// ---------------------------------------------------------------------------
__global__ __launch_bounds__(256) void logit_kernel(
    const float* __restrict__ Nm, const float* __restrict__ W1,
    const float* __restrict__ w2, float* __restrict__ logit, int n_nodes) {
  __shared__ float w1t[32 * 129];
  const int tid = threadIdx.x;
  const int j = tid & 127;
  const int half = tid >> 7;
  const int base = blockIdx.x * NPB;
  float acc[8];
#pragma unroll
  for (int g = 0; g < 8; ++g) acc[g] = 0.f;
  for (int c = 0; c < 4; ++c) {
    __syncthreads();
    for (int idx = tid; idx < 128 * 32; idx += 256) {
      int kl = idx & 31, jj = idx >> 5;
      w1t[kl * 129 + jj] = W1[jj * 128 + c * 32 + kl];
    }
    __syncthreads();
#pragma unroll
    for (int g = 0; g < 8; ++g) {
      int node = base + g * 2 + half;
      if (node < n_nodes) {
        const float4* nrow =
            reinterpret_cast<const float4*>(Nm + (size_t)node * D + c * 32);
        float a = acc[g];
#pragma unroll
        for (int k4 = 0; k4 < 8; ++k4) {
          float4 nv = nrow[k4];
          int kl = k4 * 4;
          a += nv.x * w1t[(kl + 0) * 129 + j];
          a += nv.y * w1t[(kl + 1) * 129 + j];
          a += nv.z * w1t[(kl + 2) * 129 + j];
          a += nv.w * w1t[(kl + 3) * 129 + j];
        }
        acc[g] = a;
      }
    }
  }
  const float w2j = w2[j];
#pragma unroll
  for (int g = 0; g < 8; ++g) {
    int node = base + g * 2 + half;
    float t = tanhf(acc[g]) * w2j;
#pragma unroll
    for (int off = 32; off; off >>= 1) t += __shfl_down(t, off);
    if ((tid & 63) == 0 && node < n_nodes) atomicAdd(&logit[node], t);
  }
}

// ---------------------------------------------------------------------------
// CSR build: histogram -> hierarchical exclusive scan -> fill sorted arrays
// ---------------------------------------------------------------------------
__global__ __launch_bounds__(256) void hist_kernel(const int* __restrict__ dst,
                                                   int* __restrict__ count,
                                                   int n_edges) {
  int e = blockIdx.x * 256 + threadIdx.x;
  if (e < n_edges) atomicAdd(&count[dst[e]], 1);
}

__global__ __launch_bounds__(256) void scanA_kernel(
    const int* __restrict__ count, int* __restrict__ offsets,
    int* __restrict__ bsums, int n) {
  __shared__ int sdata[256];
  int tid = threadIdx.x;
  int base = blockIdx.x * SCAN_ELEMS + tid * 4;
  int c0 = (base + 0 < n) ? count[base + 0] : 0;
  int c1 = (base + 1 < n) ? count[base + 1] : 0;
  int c2 = (base + 2 < n) ? count[base + 2] : 0;
  int c3 = (base + 3 < n) ? count[base + 3] : 0;
  int s = c0 + c1 + c2 + c3;
  sdata[tid] = s;
  __syncthreads();
  for (int d = 1; d < 256; d <<= 1) {
    int v = (tid >= d) ? sdata[tid - d] : 0;
    __syncthreads();
    sdata[tid] += v;
    __syncthreads();
  }
  int tb = sdata[tid] - s;
  if (base + 0 < n) offsets[base + 0] = tb;
  if (base + 1 < n) offsets[base + 1] = tb + c0;
  if (base + 2 < n) offsets[base + 2] = tb + c0 + c1;
  if (base + 3 < n) offsets[base + 3] = tb + c0 + c1 + c2;
  if (tid == 255) bsums[blockIdx.x] = sdata[255];
}

__global__ void scanB_kernel(int* __restrict__ bsums, int nb) {
  if (threadIdx.x == 0 && blockIdx.x == 0) {
    int run = 0;
    for (int i = 0; i < nb; ++i) {
      int t = bsums[i];
      bsums[i] = run;
      run += t;
    }
  }
}

__global__ __launch_bounds__(256) void scanC_kernel(
    int* __restrict__ offsets, const int* __restrict__ bsums,
    int* __restrict__ cursor, int n, int n_edges) {
  int base = blockIdx.x * SCAN_ELEMS + threadIdx.x * 4;
  int add = bsums[blockIdx.x];
#pragma unroll
  for (int k = 0; k < 4; ++k) {
    int idx = base + k;
    if (idx < n) {
      int v = offsets[idx] + add;
      offsets[idx] = v;
      cursor[idx] = v;
    }
  }
  if (blockIdx.x == 0 && threadIdx.x == 0) offsets[n] = n_edges;
}

__global__ __launch_bounds__(256) void fill_kernel(
    const int* __restrict__ src, const int* __restrict__ dst,
    const float* __restrict__ logit, int* __restrict__ cursor,
    int* __restrict__ ssrc, float* __restrict__ sex, int n_edges) {
  int e = blockIdx.x * 256 + threadIdx.x;
  if (e < n_edges) {
    int d = dst[e];
    int s = src[e];
    int pos = atomicAdd(&cursor[d], 1);
    ssrc[pos] = s;
    sex[pos] = expf(logit[s]);
  }
}

// ---------------------------------------------------------------------------
// Accumulate: one wave per dst node, register accumulation, one write per row
// ---------------------------------------------------------------------------
__global__ __launch_bounds__(256) void accum_kernel(
    const int* __restrict__ offsets, const int* __restrict__ ssrc,
    const float* __restrict__ sex, const float* __restrict__ Nm,
    float* __restrict__ out, int n_nodes) {
  int node = (blockIdx.x * 256 + threadIdx.x) >> 6;
  int lane = threadIdx.x & 63;
  if (node >= n_nodes) return;
  int beg = offsets[node];
  int end = offsets[node + 1];
  float acc0 = 0.f, acc1 = 0.f, den = 0.f;
  int e = beg;
  for (; e + 1 < end; e += 2) {
    int s0 = ssrc[e], s1 = ssrc[e + 1];
    float x0 = sex[e], x1 = sex[e + 1];
    float a00 = Nm[(size_t)s0 * D + lane];
    float a01 = Nm[(size_t)s0 * D + 64 + lane];
    float a10 = Nm[(size_t)s1 * D + lane];
    float a11 = Nm[(size_t)s1 * D + 64 + lane];
    den += x0 + x1;
    acc0 += x0 * a00 + x1 * a10;
    acc1 += x0 * a01 + x1 * a11;
  }
  if (e < end) {
    int s0 = ssrc[e];
    float x0 = sex[e];
    den += x0;
    acc0 += x0 * Nm[(size_t)s0 * D + lane];
    acc1 += x0 * Nm[(size_t)s0 * D + 64 + lane];
  }
  float inv = (end > beg) ? 1.0f / den : 0.f;
  out[(size_t)node * D + lane] = acc0 * inv;
  out[(size_t)node * D + 64 + lane] = acc1 * inv;
}

// ---------------------------------------------------------------------------
// Fallback path (R1): per-edge atomics — used only if ws_size is too small.
// ---------------------------------------------------------------------------
__global__ __launch_bounds__(256) void denom_kernel(
    const int* __restrict__ src, const int* __restrict__ dst,
    const float* __restrict__ logit, float* __restrict__ denom, int n_edges) {
  int e = blockIdx.x * 256 + threadIdx.x;
  if (e < n_edges) {
    float ex = expf(logit[src[e]]);
    atomicAdd(&denom[dst[e]], ex);
  }
}

__global__ __launch_bounds__(256) void scatter_kernel(
    const int* __restrict__ src, const int* __restrict__ dst,
    const float* __restrict__ logit, const float* __restrict__ denom,
    const float* __restrict__ Nm, float* __restrict__ out, int n_edges) {
  int wave = (blockIdx.x * 256 + threadIdx.x) >> 6;
  int lane = threadIdx.x & 63;
  if (wave >= n_edges) return;
  int s = src[wave];
  int d = dst[wave];
  float a = expf(logit[s]) / denom[d];
  float v0 = Nm[(size_t)s * D + lane];
  float v1 = Nm[(size_t)s * D + 64 + lane];
  atomicAdd(&out[(size_t)d * D + lane], a * v0);
  atomicAdd(&out[(size_t)d * D + 64 + lane], a * v1);
}

static inline char* align_up(char* p, size_t a) {
  return (char*)(((uintptr_t)p + a - 1) & ~(uintptr_t)(a - 1));
}

extern "C" void kernel_launch(void* const* d_in, const int* in_sizes, int n_in,
                              void* d_out, int out_size, void* d_ws,
                              size_t ws_size, hipStream_t stream) {
  const float* Nm  = (const float*)d_in[0];
  const float* W1  = (const float*)d_in[1];
  const float* w2  = (const float*)d_in[2];
  const int*   src = (const int*)d_in[3];
  const int*   dst = (const int*)d_in[4];
  float* out = (float*)d_out;

  const int n_nodes = in_sizes[0] / D;
  const int n_edges = in_sizes[3];
  const int n_pad = (n_nodes + 63) & ~63;
  const int nb_scan = (n_nodes + SCAN_ELEMS - 1) / SCAN_ELEMS;

  // carve workspace
  char* p = (char*)d_ws;
  float* logit = (float*)p;      p = align_up(p + (size_t)n_pad * 4, 256);
  unsigned short* w1hi = (unsigned short*)p; p = align_up(p + 128 * 128 * 2, 256);
  unsigned short* w1lo = (unsigned short*)p; p = align_up(p + 128 * 128 * 2, 256);
  int* count   = (int*)p;        p = align_up(p + (size_t)n_nodes * 4, 256);
  int* offsets = (int*)p;        p = align_up(p + (size_t)(n_nodes + 1) * 4, 256);
  int* cursor  = (int*)p;        p = align_up(p + (size_t)n_nodes * 4, 256);
  int* bsums   = (int*)p;        p = align_up(p + (size_t)nb_scan * 4, 256);
  int* ssrc    = (int*)p;        p = align_up(p + (size_t)n_edges * 4, 256);
  float* sex   = (float*)p;      p = align_up(p + (size_t)n_edges * 4, 256);
  size_t needed = (size_t)(p - (char*)d_ws);

  hipMemsetAsync(logit, 0, (size_t)n_pad * sizeof(float), stream);

  int eblk = (n_edges + 255) / 256;

  if (ws_size >= needed) {
    // ---- MFMA logit ----
    w1_convert_kernel<<<64, 256, 0, stream>>>(W1, w1hi, w1lo);
    int nblk1 = (n_nodes + 63) / 64;
    logit_mfma_kernel<<<nblk1, 256, 0, stream>>>(Nm, w1hi, w1lo, w2, logit,
                                                 n_nodes);
    // ---- CSR path ----
    hipMemsetAsync(count, 0, (size_t)n_nodes * sizeof(int), stream);
    hist_kernel<<<eblk, 256, 0, stream>>>(dst, count, n_edges);
    scanA_kernel<<<nb_scan, 256, 0, stream>>>(count, offsets, bsums, n_nodes);
    scanB_kernel<<<1, 64, 0, stream>>>(bsums, nb_scan);
    scanC_kernel<<<nb_scan, 256, 0, stream>>>(offsets, bsums, cursor, n_nodes,
                                              n_edges);
    fill_kernel<<<eblk, 256, 0, stream>>>(src, dst, logit, cursor, ssrc, sex,
                                          n_edges);
    int ablk = (n_nodes + 3) / 4;
    accum_kernel<<<ablk, 256, 0, stream>>>(offsets, ssrc, sex, Nm, out,
                                           n_nodes);
  } else {
    // ---- fallback: scalar logit + R1 atomic path ----
    int nblk1 = (n_nodes + NPB - 1) / NPB;
    logit_kernel<<<nblk1, 256, 0, stream>>>(Nm, W1, w2, logit, n_nodes);
    float* denom = logit + n_pad;
    hipMemsetAsync(denom, 0, (size_t)n_pad * sizeof(float), stream);
    hipMemsetAsync(out, 0, (size_t)out_size * sizeof(float), stream);
    denom_kernel<<<eblk, 256, 0, stream>>>(src, dst, logit, denom, n_edges);
    int nblk3 = (n_edges + 3) / 4;
    scatter_kernel<<<nblk3, 256, 0, stream>>>(src, dst, logit, denom, Nm, out,
                                              n_edges);
  }
}

// Round 4
// 187.651 us; speedup vs baseline: 2.6836x; 1.0126x over previous
//
#include <hip/hip_runtime.h>
#include <hip/hip_bf16.h>

#define D 128
#define NPB 16           // nodes per block in fallback logit kernel
#define SCAN_ELEMS 1024  // elements per scan block (256 thr x 4)

typedef __attribute__((ext_vector_type(8))) short bf16x8;
typedef __attribute__((ext_vector_type(4))) float f32x4;

__device__ __forceinline__ unsigned short f2bf_rne(float f) {
  unsigned u = __float_as_uint(f);
  unsigned r = (u + 0x7FFFu + ((u >> 16) & 1u)) >> 16;
  return (unsigned short)r;
}

__device__ __forceinline__ float fast_tanh(float x) {
  float e = __expf(2.0f * x);
  return 1.0f - 2.0f / (e + 1.0f);
}

// ---------------------------------------------------------------------------
// W1 -> bf16 hi/lo split (one-time, 16384 elements)
// ---------------------------------------------------------------------------
__global__ __launch_bounds__(256) void w1_convert_kernel(
    const float* __restrict__ W1, unsigned short* __restrict__ w1hi,
    unsigned short* __restrict__ w1lo) {
  int i = blockIdx.x * 256 + threadIdx.x;
  float x = W1[i];
  unsigned short h = f2bf_rne(x);
  float hf = __uint_as_float((unsigned)h << 16);
  w1hi[i] = h;
  w1lo[i] = f2bf_rne(x - hf);
}

// ---------------------------------------------------------------------------
// N -> bf16 (for the accum gather; halves gather bytes, L3-resident)
// ---------------------------------------------------------------------------
__global__ __launch_bounds__(256) void n_convert_kernel(
    const float* __restrict__ Nm, unsigned short* __restrict__ nbf,
    int total4) {
  int stride = gridDim.x * 256;
  for (int i = blockIdx.x * 256 + threadIdx.x; i < total4; i += stride) {
    float4 v = *(const float4*)(Nm + (size_t)i * 4);
    *(ushort4*)(nbf + (size_t)i * 4) =
        make_ushort4(f2bf_rne(v.x), f2bf_rne(v.y), f2bf_rne(v.z),
                     f2bf_rne(v.w));
  }
}

// ---------------------------------------------------------------------------
// explog[i] = exp(logit[i])  (tiny; runs after logit kernel)
// ---------------------------------------------------------------------------
__global__ __launch_bounds__(256) void exp_kernel(
    const float* __restrict__ logit, float* __restrict__ explog, int n) {
  int i = blockIdx.x * 256 + threadIdx.x;
  if (i < n) explog[i] = expf(logit[i]);
}

// ---------------------------------------------------------------------------
// logit via split-bf16 MFMA (unchanged from R3 — verified)
// ---------------------------------------------------------------------------
__global__ __launch_bounds__(256, 2) void logit_mfma_kernel(
    const float* __restrict__ Nm, const unsigned short* __restrict__ w1hi,
    const unsigned short* __restrict__ w1lo, const float* __restrict__ w2,
    float* __restrict__ logit, int n_nodes) {
  __shared__ unsigned short lhi[64 * 128];
  __shared__ unsigned short llo[64 * 128];
  const int tid = threadIdx.x;
  const int w = tid >> 6;
  const int l = tid & 63;
  const int lg = l >> 4;
  const int ln = l & 15;
  const int base = blockIdx.x * 64;

  bf16x8 Bh[2][4], Bl[2][4];
#pragma unroll
  for (int ntl = 0; ntl < 2; ++ntl) {
    int n = (w * 2 + ntl) * 16 + ln;
#pragma unroll
    for (int kt = 0; kt < 4; ++kt) {
      int k = kt * 32 + lg * 8;
      Bh[ntl][kt] = *(const bf16x8*)(w1hi + n * 128 + k);
      Bl[ntl][kt] = *(const bf16x8*)(w1lo + n * 128 + k);
    }
  }

#pragma unroll
  for (int i = 0; i < 8; ++i) {
    int flat = tid + i * 256;
    int row = flat >> 5;
    int c4 = flat & 31;
    int grow = base + row;
    if (grow >= n_nodes) grow = n_nodes - 1;
    float4 v = *(const float4*)(Nm + (size_t)grow * D + c4 * 4);
    unsigned short h0 = f2bf_rne(v.x), h1 = f2bf_rne(v.y);
    unsigned short h2 = f2bf_rne(v.z), h3 = f2bf_rne(v.w);
    unsigned short o0 = f2bf_rne(v.x - __uint_as_float((unsigned)h0 << 16));
    unsigned short o1 = f2bf_rne(v.y - __uint_as_float((unsigned)h1 << 16));
    unsigned short o2 = f2bf_rne(v.z - __uint_as_float((unsigned)h2 << 16));
    unsigned short o3 = f2bf_rne(v.w - __uint_as_float((unsigned)h3 << 16));
    int boff = (c4 * 8) ^ ((row & 7) << 4);
    *(ushort4*)((char*)lhi + row * 256 + boff) = make_ushort4(h0, h1, h2, h3);
    *(ushort4*)((char*)llo + row * 256 + boff) = make_ushort4(o0, o1, o2, o3);
  }
  __syncthreads();

  f32x4 acc[4][2];
#pragma unroll
  for (int mt = 0; mt < 4; ++mt)
#pragma unroll
    for (int ntl = 0; ntl < 2; ++ntl) acc[mt][ntl] = (f32x4){0.f, 0.f, 0.f, 0.f};

#pragma unroll
  for (int mt = 0; mt < 4; ++mt) {
    int row = mt * 16 + ln;
    bf16x8 Ah[4], Al[4];
#pragma unroll
    for (int kt = 0; kt < 4; ++kt) {
      int boff = (kt * 64 + lg * 16) ^ ((row & 7) << 4);
      Ah[kt] = *(const bf16x8*)((const char*)lhi + row * 256 + boff);
      Al[kt] = *(const bf16x8*)((const char*)llo + row * 256 + boff);
    }
#pragma unroll
    for (int ntl = 0; ntl < 2; ++ntl) {
#pragma unroll
      for (int kt = 0; kt < 4; ++kt) {
        acc[mt][ntl] = __builtin_amdgcn_mfma_f32_16x16x32_bf16(
            Ah[kt], Bh[ntl][kt], acc[mt][ntl], 0, 0, 0);
        acc[mt][ntl] = __builtin_amdgcn_mfma_f32_16x16x32_bf16(
            Ah[kt], Bl[ntl][kt], acc[mt][ntl], 0, 0, 0);
        acc[mt][ntl] = __builtin_amdgcn_mfma_f32_16x16x32_bf16(
            Al[kt], Bh[ntl][kt], acc[mt][ntl], 0, 0, 0);
      }
    }
  }

  float w2a = w2[(w * 2 + 0) * 16 + ln];
  float w2b = w2[(w * 2 + 1) * 16 + ln];
#pragma unroll
  for (int mt = 0; mt < 4; ++mt) {
    float s0 = fast_tanh(acc[mt][0][0]) * w2a + fast_tanh(acc[mt][1][0]) * w2b;
    float s1 = fast_tanh(acc[mt][0][1]) * w2a + fast_tanh(acc[mt][1][1]) * w2b;
    float s2 = fast_tanh(acc[mt][0][2]) * w2a + fast_tanh(acc[mt][1][2]) * w2b;
    float s3 = fast_tanh(acc[mt][0][3]) * w2a + fast_tanh(acc[mt][1][3]) * w2b;
#pragma unroll
    for (int mask = 1; mask < 16; mask <<= 1) {
      s0 += __shfl_xor(s0, mask);
      s1 += __shfl_xor(s1, mask);
      s2 += __shfl_xor(s2, mask);
      s3 += __shfl_xor(s3, mask);
    }
    if (ln < 4) {
      float sv = (ln == 0) ? s0 : (ln == 1) ? s1 : (ln == 2) ? s2 : s3;
      int node = base + mt * 16 + lg * 4 + ln;
      if (node < n_nodes) atomicAdd(&logit[node], sv);
    }
  }
}

// ---------------------------------------------------------------------------
// Fallback scalar logit kernel
// ---------------------------------------------------------------------------
__global__ __launch_bounds__(256) void logit_kernel(
    const float* __restrict__ Nm, const float* __restrict__ W1,
    const float* __restrict__ w2, float* __restrict__ logit, int n_nodes) {
  __shared__ float w1t[32 * 129];
  const int tid = threadIdx.x;
  const int j = tid & 127;
  const int half = tid >> 7;
  const int base = blockIdx.x * NPB;
  float acc[8];
#pragma unroll
  for (int g = 0; g < 8; ++g) acc[g] = 0.f;
  for (int c = 0; c < 4; ++c) {
    __syncthreads();
    for (int idx = tid; idx < 128 * 32; idx += 256) {
      int kl = idx & 31, jj = idx >> 5;
      w1t[kl * 129 + jj] = W1[jj * 128 + c * 32 + kl];
    }
    __syncthreads();
#pragma unroll
    for (int g = 0; g < 8; ++g) {
      int node = base + g * 2 + half;
      if (node < n_nodes) {
        const float4* nrow =
            reinterpret_cast<const float4*>(Nm + (size_t)node * D + c * 32);
        float a = acc[g];
#pragma unroll
        for (int k4 = 0; k4 < 8; ++k4) {
          float4 nv = nrow[k4];
          int kl = k4 * 4;
          a += nv.x * w1t[(kl + 0) * 129 + j];
          a += nv.y * w1t[(kl + 1) * 129 + j];
          a += nv.z * w1t[(kl + 2) * 129 + j];
          a += nv.w * w1t[(kl + 3) * 129 + j];
        }
        acc[g] = a;
      }
    }
  }
  const float w2j = w2[j];
#pragma unroll
  for (int g = 0; g < 8; ++g) {
    int node = base + g * 2 + half;
    float t = tanhf(acc[g]) * w2j;
#pragma unroll
    for (int off = 32; off; off >>= 1) t += __shfl_down(t, off);
    if ((tid & 63) == 0 && node < n_nodes) atomicAdd(&logit[node], t);
  }
}

// ---------------------------------------------------------------------------
// CSR build: histogram -> hierarchical exclusive scan -> fill (src only, 4B)
// ---------------------------------------------------------------------------
__global__ __launch_bounds__(256) void hist_kernel(const int* __restrict__ dst,
                                                   int* __restrict__ count,
                                                   int n_edges) {
  int e = blockIdx.x * 256 + threadIdx.x;
  if (e < n_edges) atomicAdd(&count[dst[e]], 1);
}

__global__ __launch_bounds__(256) void scanA_kernel(
    const int* __restrict__ count, int* __restrict__ offsets,
    int* __restrict__ bsums, int n) {
  __shared__ int sdata[256];
  int tid = threadIdx.x;
  int base = blockIdx.x * SCAN_ELEMS + tid * 4;
  int c0 = (base + 0 < n) ? count[base + 0] : 0;
  int c1 = (base + 1 < n) ? count[base + 1] : 0;
  int c2 = (base + 2 < n) ? count[base + 2] : 0;
  int c3 = (base + 3 < n) ? count[base + 3] : 0;
  int s = c0 + c1 + c2 + c3;
  sdata[tid] = s;
  __syncthreads();
  for (int d = 1; d < 256; d <<= 1) {
    int v = (tid >= d) ? sdata[tid - d] : 0;
    __syncthreads();
    sdata[tid] += v;
    __syncthreads();
  }
  int tb = sdata[tid] - s;
  if (base + 0 < n) offsets[base + 0] = tb;
  if (base + 1 < n) offsets[base + 1] = tb + c0;
  if (base + 2 < n) offsets[base + 2] = tb + c0 + c1;
  if (base + 3 < n) offsets[base + 3] = tb + c0 + c1 + c2;
  if (tid == 255) bsums[blockIdx.x] = sdata[255];
}

__global__ void scanB_kernel(int* __restrict__ bsums, int nb) {
  if (threadIdx.x == 0 && blockIdx.x == 0) {
    int run = 0;
    for (int i = 0; i < nb; ++i) {
      int t = bsums[i];
      bsums[i] = run;
      run += t;
    }
  }
}

__global__ __launch_bounds__(256) void scanC_kernel(
    int* __restrict__ offsets, const int* __restrict__ bsums,
    int* __restrict__ cursor, int n, int n_edges) {
  int base = blockIdx.x * SCAN_ELEMS + threadIdx.x * 4;
  int add = bsums[blockIdx.x];
#pragma unroll
  for (int k = 0; k < 4; ++k) {
    int idx = base + k;
    if (idx < n) {
      int v = offsets[idx] + add;
      offsets[idx] = v;
      cursor[idx] = v;
    }
  }
  if (blockIdx.x == 0 && threadIdx.x == 0) offsets[n] = n_edges;
}

__global__ __launch_bounds__(256) void fill_kernel(
    const int* __restrict__ src, const int* __restrict__ dst,
    int* __restrict__ cursor, int* __restrict__ ssrc, int n_edges) {
  int e = blockIdx.x * 256 + threadIdx.x;
  if (e < n_edges) {
    int d = dst[e];
    int pos = atomicAdd(&cursor[d], 1);
    ssrc[pos] = src[e];
  }
}

// ---------------------------------------------------------------------------
// Accumulate, bf16 gather: one wave per dst node; lane covers 2 features via
// one 4B load (two packed bf16). explog gathered from L2 (200 KB table).
// ---------------------------------------------------------------------------
__global__ __launch_bounds__(256) void accum_bf16_kernel(
    const int* __restrict__ offsets, const int* __restrict__ ssrc,
    const float* __restrict__ explog, const unsigned short* __restrict__ nbf,
    float* __restrict__ out, int n_nodes) {
  int node = (blockIdx.x * 256 + threadIdx.x) >> 6;
  int lane = threadIdx.x & 63;
  if (node >= n_nodes) return;
  int beg = offsets[node];
  int end = offsets[node + 1];
  float acc0 = 0.f, acc1 = 0.f, den = 0.f;
  int e = beg;
  for (; e + 1 < end; e += 2) {
    int s0 = ssrc[e], s1 = ssrc[e + 1];
    float x0 = explog[s0], x1 = explog[s1];
    unsigned u0 = *(const unsigned*)(nbf + (size_t)s0 * D + lane * 2);
    unsigned u1 = *(const unsigned*)(nbf + (size_t)s1 * D + lane * 2);
    float a00 = __uint_as_float(u0 << 16);
    float a01 = __uint_as_float(u0 & 0xFFFF0000u);
    float a10 = __uint_as_float(u1 << 16);
    float a11 = __uint_as_float(u1 & 0xFFFF0000u);
    den += x0 + x1;
    acc0 += x0 * a00 + x1 * a10;
    acc1 += x0 * a01 + x1 * a11;
  }
  if (e < end) {
    int s0 = ssrc[e];
    float x0 = explog[s0];
    unsigned u0 = *(const unsigned*)(nbf + (size_t)s0 * D + lane * 2);
    den += x0;
    acc0 += x0 * __uint_as_float(u0 << 16);
    acc1 += x0 * __uint_as_float(u0 & 0xFFFF0000u);
  }
  float inv = (end > beg) ? 1.0f / den : 0.f;
  *(float2*)(out + (size_t)node * D + lane * 2) =
      make_float2(acc0 * inv, acc1 * inv);
}

// f32-gather variant (mid tier, if ws can't fit nbf)
__global__ __launch_bounds__(256) void accum_f32_kernel(
    const int* __restrict__ offsets, const int* __restrict__ ssrc,
    const float* __restrict__ explog, const float* __restrict__ Nm,
    float* __restrict__ out, int n_nodes) {
  int node = (blockIdx.x * 256 + threadIdx.x) >> 6;
  int lane = threadIdx.x & 63;
  if (node >= n_nodes) return;
  int beg = offsets[node];
  int end = offsets[node + 1];
  float acc0 = 0.f, acc1 = 0.f, den = 0.f;
  int e = beg;
  for (; e + 1 < end; e += 2) {
    int s0 = ssrc[e], s1 = ssrc[e + 1];
    float x0 = explog[s0], x1 = explog[s1];
    float a00 = Nm[(size_t)s0 * D + lane];
    float a01 = Nm[(size_t)s0 * D + 64 + lane];
    float a10 = Nm[(size_t)s1 * D + lane];
    float a11 = Nm[(size_t)s1 * D + 64 + lane];
    den += x0 + x1;
    acc0 += x0 * a00 + x1 * a10;
    acc1 += x0 * a01 + x1 * a11;
  }
  if (e < end) {
    int s0 = ssrc[e];
    float x0 = explog[s0];
    den += x0;
    acc0 += x0 * Nm[(size_t)s0 * D + lane];
    acc1 += x0 * Nm[(size_t)s0 * D + 64 + lane];
  }
  float inv = (end > beg) ? 1.0f / den : 0.f;
  out[(size_t)node * D + lane] = acc0 * inv;
  out[(size_t)node * D + 64 + lane] = acc1 * inv;
}

// ---------------------------------------------------------------------------
// Fallback path (R1): per-edge atomics
// ---------------------------------------------------------------------------
__global__ __launch_bounds__(256) void denom_kernel(
    const int* __restrict__ src, const int* __restrict__ dst,
    const float* __restrict__ logit, float* __restrict__ denom, int n_edges) {
  int e = blockIdx.x * 256 + threadIdx.x;
  if (e < n_edges) {
    float ex = expf(logit[src[e]]);
    atomicAdd(&denom[dst[e]], ex);
  }
}

__global__ __launch_bounds__(256) void scatter_kernel(
    const int* __restrict__ src, const int* __restrict__ dst,
    const float* __restrict__ logit, const float* __restrict__ denom,
    const float* __restrict__ Nm, float* __restrict__ out, int n_edges) {
  int wave = (blockIdx.x * 256 + threadIdx.x) >> 6;
  int lane = threadIdx.x & 63;
  if (wave >= n_edges) return;
  int s = src[wave];
  int d = dst[wave];
  float a = expf(logit[s]) / denom[d];
  float v0 = Nm[(size_t)s * D + lane];
  float v1 = Nm[(size_t)s * D + 64 + lane];
  atomicAdd(&out[(size_t)d * D + lane], a * v0);
  atomicAdd(&out[(size_t)d * D + 64 + lane], a * v1);
}

static inline char* align_up(char* p, size_t a) {
  return (char*)(((uintptr_t)p + a - 1) & ~(uintptr_t)(a - 1));
}

extern "C" void kernel_launch(void* const* d_in, const int* in_sizes, int n_in,
                              void* d_out, int out_size, void* d_ws,
                              size_t ws_size, hipStream_t stream) {
  const float* Nm  = (const float*)d_in[0];
  const float* W1  = (const float*)d_in[1];
  const float* w2  = (const float*)d_in[2];
  const int*   src = (const int*)d_in[3];
  const int*   dst = (const int*)d_in[4];
  float* out = (float*)d_out;

  const int n_nodes = in_sizes[0] / D;
  const int n_edges = in_sizes[3];
  const int n_pad = (n_nodes + 63) & ~63;
  const int nb_scan = (n_nodes + SCAN_ELEMS - 1) / SCAN_ELEMS;

  // carve workspace
  char* p = (char*)d_ws;
  float* logit  = (float*)p;     p = align_up(p + (size_t)n_pad * 4, 256);
  float* explog = (float*)p;     p = align_up(p + (size_t)n_pad * 4, 256);
  unsigned short* w1hi = (unsigned short*)p; p = align_up(p + 128 * 128 * 2, 256);
  unsigned short* w1lo = (unsigned short*)p; p = align_up(p + 128 * 128 * 2, 256);
  int* count   = (int*)p;        p = align_up(p + (size_t)n_nodes * 4, 256);
  int* offsets = (int*)p;        p = align_up(p + (size_t)(n_nodes + 1) * 4, 256);
  int* cursor  = (int*)p;        p = align_up(p + (size_t)n_nodes * 4, 256);
  int* bsums   = (int*)p;        p = align_up(p + (size_t)nb_scan * 4, 256);
  int* ssrc    = (int*)p;        p = align_up(p + (size_t)n_edges * 4, 256);
  size_t needed_mid = (size_t)(p - (char*)d_ws);
  unsigned short* nbf = (unsigned short*)p;
  p = align_up(p + (size_t)n_nodes * D * 2, 256);
  size_t needed_full = (size_t)(p - (char*)d_ws);

  hipMemsetAsync(logit, 0, (size_t)n_pad * sizeof(float), stream);

  int eblk = (n_edges + 255) / 256;
  int nblkE = (n_nodes + 255) / 256;

  if (ws_size >= needed_mid) {
    // ---- MFMA logit ----
    w1_convert_kernel<<<64, 256, 0, stream>>>(W1, w1hi, w1lo);
    int nblk1 = (n_nodes + 63) / 64;
    logit_mfma_kernel<<<nblk1, 256, 0, stream>>>(Nm, w1hi, w1lo, w2, logit,
                                                 n_nodes);
    exp_kernel<<<nblkE, 256, 0, stream>>>(logit, explog, n_nodes);

    // ---- CSR build ----
    hipMemsetAsync(count, 0, (size_t)n_nodes * sizeof(int), stream);
    hist_kernel<<<eblk, 256, 0, stream>>>(dst, count, n_edges);
    scanA_kernel<<<nb_scan, 256, 0, stream>>>(count, offsets, bsums, n_nodes);
    scanB_kernel<<<1, 64, 0, stream>>>(bsums, nb_scan);
    scanC_kernel<<<nb_scan, 256, 0, stream>>>(offsets, bsums, cursor, n_nodes,
                                              n_edges);
    fill_kernel<<<eblk, 256, 0, stream>>>(src, dst, cursor, ssrc, n_edges);

    int ablk = (n_nodes + 3) / 4;
    if (ws_size >= needed_full) {
      int total4 = n_nodes * D / 4;
      n_convert_kernel<<<2048, 256, 0, stream>>>(Nm, nbf, total4);
      accum_bf16_kernel<<<ablk, 256, 0, stream>>>(offsets, ssrc, explog, nbf,
                                                  out, n_nodes);
    } else {
      accum_f32_kernel<<<ablk, 256, 0, stream>>>(offsets, ssrc, explog, Nm,
                                                 out, n_nodes);
    }
  } else {
    // ---- fallback: scalar logit + R1 atomic path ----
    int nblk1 = (n_nodes + NPB - 1) / NPB;
    logit_kernel<<<nblk1, 256, 0, stream>>>(Nm, W1, w2, logit, n_nodes);
    float* denom = logit + n_pad;
    hipMemsetAsync(denom, 0, (size_t)n_pad * sizeof(float), stream);
    hipMemsetAsync(out, 0, (size_t)out_size * sizeof(float), stream);
    denom_kernel<<<eblk, 256, 0, stream>>>(src, dst, logit, denom, n_edges);
    int nblk3 = (n_edges + 3) / 4;
    scatter_kernel<<<nblk3, 256, 0, stream>>>(src, dst, logit, denom, Nm, out,
                                              n_edges);
  }
}